// Round 1
// baseline (206.633 us; speedup 1.0000x reference)
//
#include <hip/hip_runtime.h>

#define BATCH 512
#define GRID_N 25
#define NODES 625            // 25*25
#define BN (BATCH * NODES)   // 320000
#define NTILES (BN / 16)     // 20000
#define F 66
#define D 64
#define WPB 4                // waves per block
#define TPW 2                // tiles per wave
#define NT_BLK (WPB * TPW)   // 8 tiles (128 nodes) per block
#define STAGE_F (NT_BLK * 16 * F)     // 8448 floats = 33792 B staged per block
#define NBLOCKS (NTILES / NT_BLK)     // 2500  (2500*33792 B == 84,480,000 B == sizeof(x), exact)

typedef short bf16x8 __attribute__((ext_vector_type(8)));  // 8 bf16 bits (4 VGPRs)
typedef float f32x4  __attribute__((ext_vector_type(4)));

// fp32 -> bf16 bits, round-to-nearest-even
__device__ __forceinline__ short f2bf(float f) {
    union { float f; unsigned u; } c; c.f = f;
    unsigned r = c.u + 0x7fffu + ((c.u >> 16) & 1u);
    return (short)(r >> 16);
}

// async global->LDS, 16 B per lane; LDS dest = wave-uniform base + lane*16
typedef const __attribute__((address_space(1))) void gas_void;
typedef __attribute__((address_space(3))) void las_void;
__device__ __forceinline__ void gload_lds16(const float* g, float* l) {
    __builtin_amdgcn_global_load_lds((gas_void*)g, (las_void*)l, 16, 0, 0);
}

// ---------------- Kernel A (MFMA, LDS-staged streaming):
// h = x@Wfc^T+bfc ; u=h.Wat[0:64] ; v=h.Wat[64:128]
// Block stages its full 33,792 B x-slice via global_load_lds (coalesced 1 KB/instr),
// reads MFMA A-fragments from LDS, then reuses the staging LDS as the transpose buffer.
__global__ __launch_bounds__(256, 4) void fc_mfma(
    const float* __restrict__ x, const float* __restrict__ Wfc,
    const float* __restrict__ bfc, const float* __restrict__ Wat,
    float* __restrict__ hout, float* __restrict__ u, float* __restrict__ v)
{
    const int tid  = threadIdx.x;
    const int lane = tid & 63;
    const int wid  = tid >> 6;
    const int l15  = lane & 15;
    const int quad = lane >> 4;

    __shared__ float stage[STAGE_F];    // 33,792 B; later reused: first 16 KB = transpose bufs

    const size_t base = (size_t)blockIdx.x * STAGE_F;   // float offset, 16B-aligned

    // ---- stage x: 8 full rounds (4 KB each) + 1 wave-round (1 KB) ----
#pragma unroll
    for (int it = 0; it < 8; ++it)
        gload_lds16(x + base + it * 1024 + tid * 4,
                    stage + it * 1024 + wid * 256);     // dest uniform per wave
    if (wid == 0)
        gload_lds16(x + base + 8192 + lane * 4, stage + 8192);

    // ---- per-wave weight fragments (global loads overlap the staging flight) ----
    // B[k][n=lane&15] = Wfc[n][k]
    bf16x8 bfrag[4][3];
#pragma unroll
    for (int t = 0; t < 4; ++t) {
        const float2* wr = (const float2*)Wfc + (t * 16 + l15) * 33;
#pragma unroll
        for (int c = 0; c < 2; ++c) {
            bf16x8 fr;
#pragma unroll
            for (int j2 = 0; j2 < 4; ++j2) {
                const float2 p = wr[c * 16 + quad * 4 + j2];
                fr[j2 * 2]     = f2bf(p.x);
                fr[j2 * 2 + 1] = f2bf(p.y);
            }
            bfrag[t][c] = fr;
        }
        bf16x8 z = {0, 0, 0, 0, 0, 0, 0, 0};            // K-chunk 2: only k=64,65 live
        if (quad == 0) {
            const float2 p = wr[32];
            z[0] = f2bf(p.x); z[1] = f2bf(p.y);
        }
        bfrag[t][2] = z;
    }
    float bft[4], wa1[4], wa2[4];
#pragma unroll
    for (int t = 0; t < 4; ++t) {
        bft[t] = bfc[t * 16 + l15];
        wa1[t] = Wat[t * 16 + l15];
        wa2[t] = Wat[64 + t * 16 + l15];
    }

    __syncthreads();    // drains vmcnt: staged x visible in LDS

    // ---- A fragments from LDS for BOTH tiles (8-B aligned float2 reads) ----
    // A[m=l15][k=quad*8+j]
    bf16x8 afrag[TPW][3];
#pragma unroll
    for (int t = 0; t < TPW; ++t) {
        const int node = (wid * TPW + t) * 16 + l15;    // local row in stage
        const float2* rp = (const float2*)stage + node * 33 + quad * 4;
#pragma unroll
        for (int c = 0; c < 2; ++c) {
            bf16x8 fr;
#pragma unroll
            for (int j2 = 0; j2 < 4; ++j2) {
                const float2 p = rp[c * 16 + j2];        // k = c*32 + quad*8 + 2*j2
                fr[j2 * 2]     = f2bf(p.x);
                fr[j2 * 2 + 1] = f2bf(p.y);
            }
            afrag[t][c] = fr;
        }
        bf16x8 z = {0, 0, 0, 0, 0, 0, 0, 0};
        if (quad == 0) {
            const float2 p = ((const float2*)stage)[node * 33 + 32];  // k = 64,65
            z[0] = f2bf(p.x); z[1] = f2bf(p.y);
        }
        afrag[t][2] = z;
    }

    __syncthreads();    // all fragment reads done -> safe to reuse stage as transpose buf

    float* tbuf = stage + wid * 1024;   // wave-private 4 KB

#pragma unroll
    for (int t = 0; t < TPW; ++t) {
        const int bn0 = (blockIdx.x * NT_BLK + wid * TPW + t) * 16;

        // ---- MFMA: 4 N-tiles x 3 K-chunks; C/D row=quad*4+reg, col=l15 ----
        f32x4 acc[4] = {{0,0,0,0},{0,0,0,0},{0,0,0,0},{0,0,0,0}};
#pragma unroll
        for (int nt = 0; nt < 4; ++nt)
#pragma unroll
            for (int c = 0; c < 3; ++c)
                acc[nt] = __builtin_amdgcn_mfma_f32_16x16x32_bf16(afrag[t][c], bfrag[nt][c], acc[nt], 0, 0, 0);

        // ---- epilogue: bias, u/v partials, LDS transpose, coalesced store ----
        float pu[4] = {0, 0, 0, 0}, pv[4] = {0, 0, 0, 0};
#pragma unroll
        for (int nt = 0; nt < 4; ++nt) {
#pragma unroll
            for (int r = 0; r < 4; ++r) {
                const float h = acc[nt][r] + bft[nt];
                tbuf[(quad * 4 + r) * 64 + nt * 16 + l15] = h;   // h_tile[node][ch]
                pu[r] = fmaf(h, wa1[nt], pu[r]);
                pv[r] = fmaf(h, wa2[nt], pv[r]);
            }
        }
#pragma unroll
        for (int off = 8; off > 0; off >>= 1) {
#pragma unroll
            for (int r = 0; r < 4; ++r) {
                pu[r] += __shfl_xor(pu[r], off, 64);
                pv[r] += __shfl_xor(pv[r], off, 64);
            }
        }
        if (l15 == 0) {
#pragma unroll
            for (int r = 0; r < 4; ++r) {
                u[bn0 + quad * 4 + r] = pu[r];
                v[bn0 + quad * 4 + r] = pv[r];
            }
        }
        // wave-private transpose buffer -> no barrier; in-order DS ops per wave
        float4* dst = (float4*)(hout + (size_t)bn0 * D);
        const float4* src = (const float4*)tbuf;
#pragma unroll
        for (int i = 0; i < 4; ++i)
            dst[i * 64 + lane] = src[i * 64 + lane];   // 1 KB contiguous per instr
    }
}

// ---------------- Kernel B: s[k] = leaky(u[n] + v[neigh(n,k)] + b_at); softmax over k
// wave-cooperative coalesced output via wave-private LDS
__global__ __launch_bounds__(256) void attn_kernel(
    const float* __restrict__ u, const float* __restrict__ v,
    const float* __restrict__ bat, float* __restrict__ wout)
{
    __shared__ float sw[256 * 9];
    const int tid  = threadIdx.x;
    const int lane = tid & 63;
    const int wid  = tid >> 6;
    const int bn   = blockIdx.x * 256 + tid;        // BN = 1250 * 256 exactly

    const int b   = bn / NODES;
    const int n   = bn - b * NODES;
    const int row = n / GRID_N;
    const int col = n - row * GRID_N;
    // reference's edge clamp: shift whole 3x3 window inward at the borders
    const int r0 = row + (row == 0) - (row == GRID_N - 1);
    const int c0 = col + (col == 0) - (col == GRID_N - 1);

    const float* vb = v + b * NODES;
    const float u0 = u[bn] + bat[0];

    float s[9];
#pragma unroll
    for (int k = 0; k < 9; ++k) {
        const int nr = r0 + (k / 3) - 1;
        const int nc = c0 + (k % 3) - 1;
        const float t = u0 + vb[nr * GRID_N + nc];
        s[k] = (t >= 0.0f) ? t : 0.01f * t;
    }
    float m = s[0];
#pragma unroll
    for (int k = 1; k < 9; ++k) m = fmaxf(m, s[k]);
    float sum = 0.0f;
#pragma unroll
    for (int k = 0; k < 9; ++k) { s[k] = __expf(s[k] - m); sum += s[k]; }
    const float inv = 1.0f / sum;

    float* ws = sw + wid * 576;                     // wave-private 2304 B
#pragma unroll
    for (int k = 0; k < 9; ++k) ws[lane * 9 + k] = s[k] * inv;

    // 576 floats = 144 float4 per wave, fully coalesced
    float4* dst = (float4*)(wout + (size_t)(blockIdx.x * 256 + wid * 64) * 9);
    const float4* src = (const float4*)ws;
    dst[lane]      = src[lane];
    dst[64 + lane] = src[64 + lane];
    if (lane < 16) dst[128 + lane] = src[128 + lane];
}

extern "C" void kernel_launch(void* const* d_in, const int* in_sizes, int n_in,
                              void* d_out, int out_size, void* d_ws, size_t ws_size,
                              hipStream_t stream)
{
    const float* x   = (const float*)d_in[0];
    const float* Wfc = (const float*)d_in[1];
    const float* bfc = (const float*)d_in[2];
    const float* Wat = (const float*)d_in[3];
    const float* bat = (const float*)d_in[4];

    float* hout = (float*)d_out;                       // [B, N, 64]
    float* wout = (float*)d_out + (size_t)BN * D;      // [B, N, 9]
    float* u = (float*)d_ws;                           // [B*N]
    float* v = u + BN;                                 // [B*N]

    fc_mfma<<<NBLOCKS, 256, 0, stream>>>(x, Wfc, bfc, Wat, hout, u, v);
    attn_kernel<<<BN / 256, 256, 0, stream>>>(u, v, bat, wout);
}

// Round 2
// 177.539 us; speedup vs baseline: 1.1639x; 1.1639x over previous
//
#include <hip/hip_runtime.h>

#define BATCH 512
#define GRID_N 25
#define NODES 625            // 25*25
#define BN (BATCH * NODES)   // 320000
#define NTILES (BN / 16)     // 20000
#define F 66
#define D 64
#define WPB 4                // waves per block
#define TPW 2                // tiles per wave
#define NT_BLK (WPB * TPW)   // 8 tiles (128 nodes) per block
#define STAGE_F (NT_BLK * 16 * F)     // 8448 floats = 33792 B staged per block
#define NBLOCKS (NTILES / NT_BLK)     // 2500  (2500*33792 B == sizeof(x), exact)

typedef short bf16x8 __attribute__((ext_vector_type(8)));  // 8 bf16 bits (4 VGPRs)
typedef float f32x4  __attribute__((ext_vector_type(4)));

// fp32 -> bf16 bits, round-to-nearest-even
__device__ __forceinline__ short f2bf(float f) {
    union { float f; unsigned u; } c; c.f = f;
    unsigned r = c.u + 0x7fffu + ((c.u >> 16) & 1u);
    return (short)(r >> 16);
}

// async global->LDS, 16 B per lane; LDS dest = wave-uniform base + lane*16
typedef const __attribute__((address_space(1))) void gas_void;
typedef __attribute__((address_space(3))) void las_void;
__device__ __forceinline__ void gload_lds16(const float* g, float* l) {
    __builtin_amdgcn_global_load_lds((gas_void*)g, (las_void*)l, 16, 0, 0);
}

// ---------------- Kernel A (MFMA, LDS-staged streaming):
// h = x@Wfc^T+bfc ; u=h.Wat[0:64] ; v=h.Wat[64:128]
// Block stages its 33,792 B x-slice via global_load_lds (coalesced 1 KB/instr).
// afrag read from LDS PER TILE inside the loop (low register pressure, no spill).
// Separate 16 KB transpose buffer -> no stage reuse, no pre-barrier prefetch.
__global__ __launch_bounds__(256, 3) void fc_mfma(
    const float* __restrict__ x, const float* __restrict__ Wfc,
    const float* __restrict__ bfc, const float* __restrict__ Wat,
    float* __restrict__ hout, float* __restrict__ u, float* __restrict__ v)
{
    const int tid  = threadIdx.x;
    const int lane = tid & 63;
    const int wid  = tid >> 6;
    const int l15  = lane & 15;
    const int quad = lane >> 4;

    __shared__ float stage[STAGE_F];        // 33,792 B staged x
    __shared__ float smem[WPB * 1024];      // 16,384 B wave-private transpose bufs

    const size_t base = (size_t)blockIdx.x * STAGE_F;   // float offset, 16B-aligned

    // ---- stage x: 8 full rounds (4 KB each) + 1 wave-round (1 KB) ----
#pragma unroll
    for (int it = 0; it < 8; ++it)
        gload_lds16(x + base + it * 1024 + tid * 4,
                    stage + it * 1024 + wid * 256);     // dest uniform per wave
    if (wid == 0)
        gload_lds16(x + base + 8192 + lane * 4, stage + 8192);

    // ---- per-wave weight fragments (global loads overlap the staging flight) ----
    // B[k][n=lane&15] = Wfc[n][k]
    bf16x8 bfrag[4][3];
#pragma unroll
    for (int t = 0; t < 4; ++t) {
        const float2* wr = (const float2*)Wfc + (t * 16 + l15) * 33;
#pragma unroll
        for (int c = 0; c < 2; ++c) {
            bf16x8 fr;
#pragma unroll
            for (int j2 = 0; j2 < 4; ++j2) {
                const float2 p = wr[c * 16 + quad * 4 + j2];
                fr[j2 * 2]     = f2bf(p.x);
                fr[j2 * 2 + 1] = f2bf(p.y);
            }
            bfrag[t][c] = fr;
        }
        bf16x8 z = {0, 0, 0, 0, 0, 0, 0, 0};            // K-chunk 2: only k=64,65 live
        if (quad == 0) {
            const float2 p = wr[32];
            z[0] = f2bf(p.x); z[1] = f2bf(p.y);
        }
        bfrag[t][2] = z;
    }
    float bft[4], wa1[4], wa2[4];
#pragma unroll
    for (int t = 0; t < 4; ++t) {
        bft[t] = bfc[t * 16 + l15];
        wa1[t] = Wat[t * 16 + l15];
        wa2[t] = Wat[64 + t * 16 + l15];
    }

    __syncthreads();    // drains vmcnt: staged x visible in LDS

    float* tbuf = smem + wid * 1024;        // wave-private 4 KB

#pragma unroll
    for (int t = 0; t < TPW; ++t) {
        const int bn0 = (blockIdx.x * NT_BLK + wid * TPW + t) * 16;

        // ---- A fragments from LDS (8-B aligned float2 reads, ~4-way bank alias max) ----
        // A[m=l15][k=quad*8+j]
        const int node = (wid * TPW + t) * 16 + l15;    // local row in stage
        const float2* rp = (const float2*)stage + node * 33 + quad * 4;
        bf16x8 afrag[3];
#pragma unroll
        for (int c = 0; c < 2; ++c) {
            bf16x8 fr;
#pragma unroll
            for (int j2 = 0; j2 < 4; ++j2) {
                const float2 p = rp[c * 16 + j2];        // k = c*32 + quad*8 + 2*j2
                fr[j2 * 2]     = f2bf(p.x);
                fr[j2 * 2 + 1] = f2bf(p.y);
            }
            afrag[c] = fr;
        }
        {
            bf16x8 z = {0, 0, 0, 0, 0, 0, 0, 0};
            if (quad == 0) {
                const float2 p = ((const float2*)stage)[node * 33 + 32];  // k = 64,65
                z[0] = f2bf(p.x); z[1] = f2bf(p.y);
            }
            afrag[2] = z;
        }

        // ---- MFMA: 4 N-tiles x 3 K-chunks; C/D row=quad*4+reg, col=l15 ----
        f32x4 acc[4] = {{0,0,0,0},{0,0,0,0},{0,0,0,0},{0,0,0,0}};
#pragma unroll
        for (int nt = 0; nt < 4; ++nt)
#pragma unroll
            for (int c = 0; c < 3; ++c)
                acc[nt] = __builtin_amdgcn_mfma_f32_16x16x32_bf16(afrag[c], bfrag[nt][c], acc[nt], 0, 0, 0);

        // ---- epilogue: bias, u/v partials, LDS transpose, coalesced store ----
        float pu[4] = {0, 0, 0, 0}, pv[4] = {0, 0, 0, 0};
#pragma unroll
        for (int nt = 0; nt < 4; ++nt) {
#pragma unroll
            for (int r = 0; r < 4; ++r) {
                const float h = acc[nt][r] + bft[nt];
                tbuf[(quad * 4 + r) * 64 + nt * 16 + l15] = h;   // h_tile[node][ch]
                pu[r] = fmaf(h, wa1[nt], pu[r]);
                pv[r] = fmaf(h, wa2[nt], pv[r]);
            }
        }
#pragma unroll
        for (int off = 8; off > 0; off >>= 1) {
#pragma unroll
            for (int r = 0; r < 4; ++r) {
                pu[r] += __shfl_xor(pu[r], off, 64);
                pv[r] += __shfl_xor(pv[r], off, 64);
            }
        }
        if (l15 == 0) {
#pragma unroll
            for (int r = 0; r < 4; ++r) {
                u[bn0 + quad * 4 + r] = pu[r];
                v[bn0 + quad * 4 + r] = pv[r];
            }
        }
        // wave-private transpose buffer -> no barrier; in-order DS ops per wave
        float4* dst = (float4*)(hout + (size_t)bn0 * D);
        const float4* src = (const float4*)tbuf;
#pragma unroll
        for (int i = 0; i < 4; ++i)
            dst[i * 64 + lane] = src[i * 64 + lane];   // 1 KB contiguous per instr
    }
}

// ---------------- Kernel B: s[k] = leaky(u[n] + v[neigh(n,k)] + b_at); softmax over k
// wave-cooperative coalesced output via wave-private LDS
__global__ __launch_bounds__(256) void attn_kernel(
    const float* __restrict__ u, const float* __restrict__ v,
    const float* __restrict__ bat, float* __restrict__ wout)
{
    __shared__ float sw[256 * 9];
    const int tid  = threadIdx.x;
    const int lane = tid & 63;
    const int wid  = tid >> 6;
    const int bn   = blockIdx.x * 256 + tid;        // BN = 1250 * 256 exactly

    const int b   = bn / NODES;
    const int n   = bn - b * NODES;
    const int row = n / GRID_N;
    const int col = n - row * GRID_N;
    // reference's edge clamp: shift whole 3x3 window inward at the borders
    const int r0 = row + (row == 0) - (row == GRID_N - 1);
    const int c0 = col + (col == 0) - (col == GRID_N - 1);

    const float* vb = v + b * NODES;
    const float u0 = u[bn] + bat[0];

    float s[9];
#pragma unroll
    for (int k = 0; k < 9; ++k) {
        const int nr = r0 + (k / 3) - 1;
        const int nc = c0 + (k % 3) - 1;
        const float t = u0 + vb[nr * GRID_N + nc];
        s[k] = (t >= 0.0f) ? t : 0.01f * t;
    }
    float m = s[0];
#pragma unroll
    for (int k = 1; k < 9; ++k) m = fmaxf(m, s[k]);
    float sum = 0.0f;
#pragma unroll
    for (int k = 0; k < 9; ++k) { s[k] = __expf(s[k] - m); sum += s[k]; }
    const float inv = 1.0f / sum;

    float* ws = sw + wid * 576;                     // wave-private 2304 B
#pragma unroll
    for (int k = 0; k < 9; ++k) ws[lane * 9 + k] = s[k] * inv;

    // 576 floats = 144 float4 per wave, fully coalesced
    float4* dst = (float4*)(wout + (size_t)(blockIdx.x * 256 + wid * 64) * 9);
    const float4* src = (const float4*)ws;
    dst[lane]      = src[lane];
    dst[64 + lane] = src[64 + lane];
    if (lane < 16) dst[128 + lane] = src[128 + lane];
}

extern "C" void kernel_launch(void* const* d_in, const int* in_sizes, int n_in,
                              void* d_out, int out_size, void* d_ws, size_t ws_size,
                              hipStream_t stream)
{
    const float* x   = (const float*)d_in[0];
    const float* Wfc = (const float*)d_in[1];
    const float* bfc = (const float*)d_in[2];
    const float* Wat = (const float*)d_in[3];
    const float* bat = (const float*)d_in[4];

    float* hout = (float*)d_out;                       // [B, N, 64]
    float* wout = (float*)d_out + (size_t)BN * D;      // [B, N, 9]
    float* u = (float*)d_ws;                           // [B*N]
    float* v = u + BN;                                 // [B*N]

    fc_mfma<<<NBLOCKS, 256, 0, stream>>>(x, Wfc, bfc, Wat, hout, u, v);
    attn_kernel<<<BN / 256, 256, 0, stream>>>(u, v, bat, wout);
}

// Round 3
// 174.645 us; speedup vs baseline: 1.1832x; 1.0166x over previous
//
#include <hip/hip_runtime.h>

#define BATCH 512
#define GRID_N 25
#define NODES 625            // 25*25
#define BN (BATCH * NODES)   // 320000
#define NTILES (BN / 16)     // 20000
#define F 66
#define D 64
#define WPB 4                // waves per block
#define TPW 2                // tiles per wave per group
#define NT_GRP (WPB * TPW)   // 8 tiles (128 nodes) per group
#define GROUP_F (NT_GRP * 16 * F)   // 8448 floats per group
#define WAVE_F (TPW * 16 * F)       // 2112 floats per wave per group (8448 B)
#define G_PER_BLK 5
#define NBLOCKS_P (NTILES / (NT_GRP * G_PER_BLK))   // 500 blocks, all co-resident (2/CU)

typedef short bf16x8 __attribute__((ext_vector_type(8)));  // 8 bf16 bits (4 VGPRs)
typedef float f32x4  __attribute__((ext_vector_type(4)));

// fp32 -> bf16 bits, round-to-nearest-even
__device__ __forceinline__ short f2bf(float f) {
    union { float f; unsigned u; } c; c.f = f;
    unsigned r = c.u + 0x7fffu + ((c.u >> 16) & 1u);
    return (short)(r >> 16);
}

// async global->LDS, 16 B per active lane; LDS dest = wave-uniform base + lane*16
typedef const __attribute__((address_space(1))) void gas_void;
typedef __attribute__((address_space(3))) void las_void;
__device__ __forceinline__ void gload_lds16(const float* g, float* l) {
    __builtin_amdgcn_global_load_lds((gas_void*)g, (las_void*)l, 16, 0, 0);
}

// ---------------- Kernel A: persistent, wave-private double-buffered pipeline.
// h = x@Wfc^T+bfc ; u=h.Wat[0:64] ; v=h.Wat[64:128]
// Each wave stages ITS OWN 8448 B x-slice (9 gload_lds, last one 16-lane masked)
// into a wave-private LDS double buffer -> no barriers at all; counted
// s_waitcnt vmcnt(9) keeps next group's loads in flight across current compute.
__global__ __launch_bounds__(256, 2) void fc_mfma(
    const float* __restrict__ x, const float* __restrict__ Wfc,
    const float* __restrict__ bfc, const float* __restrict__ Wat,
    float* __restrict__ hout, float* __restrict__ u, float* __restrict__ v)
{
    const int tid  = threadIdx.x;
    const int lane = tid & 63;
    const int wid  = tid >> 6;
    const int l15  = lane & 15;
    const int quad = lane >> 4;

    __shared__ float stage[2][WPB][WAVE_F];   // 67,584 B -> 2 blocks/CU

    const int gbase = blockIdx.x * G_PER_BLK;

    // ---- stage group 0 (wave-private slice) ----
    {
        const float* src = x + (size_t)gbase * GROUP_F + wid * WAVE_F;
        float* dst = &stage[0][wid][0];
#pragma unroll
        for (int r = 0; r < 8; ++r)
            gload_lds16(src + r * 256 + lane * 4, dst + r * 256);
        if (lane < 16)
            gload_lds16(src + 2048 + lane * 4, dst + 2048);
    }

    // ---- per-wave weight fragments (overlap the staging flight) ----
    // B[k][n=lane&15] = Wfc[n][k]
    bf16x8 bfrag[4][3];
#pragma unroll
    for (int t = 0; t < 4; ++t) {
        const float2* wr = (const float2*)Wfc + (t * 16 + l15) * 33;
#pragma unroll
        for (int c = 0; c < 2; ++c) {
            bf16x8 fr;
#pragma unroll
            for (int j2 = 0; j2 < 4; ++j2) {
                const float2 p = wr[c * 16 + quad * 4 + j2];
                fr[j2 * 2]     = f2bf(p.x);
                fr[j2 * 2 + 1] = f2bf(p.y);
            }
            bfrag[t][c] = fr;
        }
        bf16x8 z = {0, 0, 0, 0, 0, 0, 0, 0};            // K-chunk 2: only k=64,65 live
        if (quad == 0) {
            const float2 p = wr[32];
            z[0] = f2bf(p.x); z[1] = f2bf(p.y);
        }
        bfrag[t][2] = z;
    }
    float bft[4], wa1[4], wa2[4];
#pragma unroll
    for (int t = 0; t < 4; ++t) {
        bft[t] = bfc[t * 16 + l15];
        wa1[t] = Wat[t * 16 + l15];
        wa2[t] = Wat[64 + t * 16 + l15];
    }

    for (int g = 0; g < G_PER_BLK; ++g) {
        const int s = g & 1;

        // prefetch next group into the other wave-private buffer, then wait
        // ONLY the old loads (counted vmcnt: the 9 new ones stay in flight)
        if (g + 1 < G_PER_BLK) {
            const float* src = x + (size_t)(gbase + g + 1) * GROUP_F + wid * WAVE_F;
            float* dst = &stage[s ^ 1][wid][0];
#pragma unroll
            for (int r = 0; r < 8; ++r)
                gload_lds16(src + r * 256 + lane * 4, dst + r * 256);
            if (lane < 16)
                gload_lds16(src + 2048 + lane * 4, dst + 2048);
            asm volatile("s_waitcnt vmcnt(9)" ::: "memory");
        } else {
            asm volatile("s_waitcnt vmcnt(0)" ::: "memory");
        }
        __builtin_amdgcn_sched_barrier(0);   // keep dependent ds_reads below the wait

        const float2* wbase = (const float2*)&stage[s][wid][0];

#pragma unroll
        for (int t = 0; t < TPW; ++t) {
            const int bn0 = ((gbase + g) * NT_GRP + wid * TPW + t) * 16;
            const int ln  = t * 16 + l15;               // local node row in wave slice

            // ---- A fragments from wave-private LDS; A[m=l15][k=quad*8+j] ----
            const float2* rp = wbase + ln * 33 + quad * 4;
            bf16x8 afrag[3];
#pragma unroll
            for (int c = 0; c < 2; ++c) {
                bf16x8 fr;
#pragma unroll
                for (int j2 = 0; j2 < 4; ++j2) {
                    const float2 p = rp[c * 16 + j2];    // k = c*32 + quad*8 + 2*j2
                    fr[j2 * 2]     = f2bf(p.x);
                    fr[j2 * 2 + 1] = f2bf(p.y);
                }
                afrag[c] = fr;
            }
            {
                bf16x8 z = {0, 0, 0, 0, 0, 0, 0, 0};
                if (quad == 0) {
                    const float2 p = wbase[ln * 33 + 32];   // k = 64,65
                    z[0] = f2bf(p.x); z[1] = f2bf(p.y);
                }
                afrag[2] = z;
            }

            // ---- MFMA: 4 N-tiles x 3 K-chunks; C/D row=quad*4+reg, col=l15 ----
            f32x4 acc[4] = {{0,0,0,0},{0,0,0,0},{0,0,0,0},{0,0,0,0}};
#pragma unroll
            for (int nt = 0; nt < 4; ++nt)
#pragma unroll
                for (int c = 0; c < 3; ++c)
                    acc[nt] = __builtin_amdgcn_mfma_f32_16x16x32_bf16(afrag[c], bfrag[nt][c], acc[nt], 0, 0, 0);

            // ---- epilogue: bias, u/v partials, DIRECT h stores (4 full 64B lines/instr) ----
            float pu[4] = {0, 0, 0, 0}, pv[4] = {0, 0, 0, 0};
#pragma unroll
            for (int nt = 0; nt < 4; ++nt) {
#pragma unroll
                for (int r = 0; r < 4; ++r) {
                    const float h = acc[nt][r] + bft[nt];
                    hout[(size_t)(bn0 + quad * 4 + r) * D + nt * 16 + l15] = h;
                    pu[r] = fmaf(h, wa1[nt], pu[r]);
                    pv[r] = fmaf(h, wa2[nt], pv[r]);
                }
            }
#pragma unroll
            for (int off = 8; off > 0; off >>= 1) {
#pragma unroll
                for (int r = 0; r < 4; ++r) {
                    pu[r] += __shfl_xor(pu[r], off, 64);
                    pv[r] += __shfl_xor(pv[r], off, 64);
                }
            }
            if (l15 == 0) {
#pragma unroll
                for (int r = 0; r < 4; ++r) {
                    u[bn0 + quad * 4 + r] = pu[r];
                    v[bn0 + quad * 4 + r] = pv[r];
                }
            }
        }
    }
}

// ---------------- Kernel B: s[k] = leaky(u[n] + v[neigh(n,k)] + b_at); softmax over k
// wave-cooperative coalesced output via wave-private LDS
__global__ __launch_bounds__(256) void attn_kernel(
    const float* __restrict__ u, const float* __restrict__ v,
    const float* __restrict__ bat, float* __restrict__ wout)
{
    __shared__ float sw[256 * 9];
    const int tid  = threadIdx.x;
    const int lane = tid & 63;
    const int wid  = tid >> 6;
    const int bn   = blockIdx.x * 256 + tid;        // BN = 1250 * 256 exactly

    const int b   = bn / NODES;
    const int n   = bn - b * NODES;
    const int row = n / GRID_N;
    const int col = n - row * GRID_N;
    // reference's edge clamp: shift whole 3x3 window inward at the borders
    const int r0 = row + (row == 0) - (row == GRID_N - 1);
    const int c0 = col + (col == 0) - (col == GRID_N - 1);

    const float* vb = v + b * NODES;
    const float u0 = u[bn] + bat[0];

    float s[9];
#pragma unroll
    for (int k = 0; k < 9; ++k) {
        const int nr = r0 + (k / 3) - 1;
        const int nc = c0 + (k % 3) - 1;
        const float t = u0 + vb[nr * GRID_N + nc];
        s[k] = (t >= 0.0f) ? t : 0.01f * t;
    }
    float m = s[0];
#pragma unroll
    for (int k = 1; k < 9; ++k) m = fmaxf(m, s[k]);
    float sum = 0.0f;
#pragma unroll
    for (int k = 0; k < 9; ++k) { s[k] = __expf(s[k] - m); sum += s[k]; }
    const float inv = 1.0f / sum;

    float* ws = sw + wid * 576;                     // wave-private 2304 B
#pragma unroll
    for (int k = 0; k < 9; ++k) ws[lane * 9 + k] = s[k] * inv;

    // 576 floats = 144 float4 per wave, fully coalesced
    float4* dst = (float4*)(wout + (size_t)(blockIdx.x * 256 + wid * 64) * 9);
    const float4* src = (const float4*)ws;
    dst[lane]      = src[lane];
    dst[64 + lane] = src[64 + lane];
    if (lane < 16) dst[128 + lane] = src[128 + lane];
}

extern "C" void kernel_launch(void* const* d_in, const int* in_sizes, int n_in,
                              void* d_out, int out_size, void* d_ws, size_t ws_size,
                              hipStream_t stream)
{
    const float* x   = (const float*)d_in[0];
    const float* Wfc = (const float*)d_in[1];
    const float* bfc = (const float*)d_in[2];
    const float* Wat = (const float*)d_in[3];
    const float* bat = (const float*)d_in[4];

    float* hout = (float*)d_out;                       // [B, N, 64]
    float* wout = (float*)d_out + (size_t)BN * D;      // [B, N, 9]
    float* u = (float*)d_ws;                           // [B*N]
    float* v = u + BN;                                 // [B*N]

    fc_mfma<<<NBLOCKS_P, 256, 0, stream>>>(x, Wfc, bfc, Wat, hout, u, v);
    attn_kernel<<<BN / 256, 256, 0, stream>>>(u, v, bat, wout);
}